// Round 2
// baseline (437.816 us; speedup 1.0000x reference)
//
#include <hip/hip_runtime.h>

#define HSZ 50
#define TSZ 512

// sigmoid(x) = 1/(1+exp(-x)); robust at extremes (exp->inf => 0, exp->0 => 1)
__device__ __forceinline__ float fast_sig(float x) {
    return __builtin_amdgcn_rcpf(1.0f + __expf(-x));
}
// tanh(x) = 1 - 2/(exp(2x)+1); robust at extremes (exp->inf => 1, exp->0 => -1)
__device__ __forceinline__ float fast_tanh(float x) {
    return fmaf(-2.0f, __builtin_amdgcn_rcpf(1.0f + __expf(2.0f * x)), 1.0f);
}

// Broadcast lane `lane`'s h to all lanes as a wave-uniform SGPR value.
// v_readlane_b32 ignores exec; lane index is a compile-time constant here.
__device__ __forceinline__ float rl(float v, int lane) {
    return __int_as_float(__builtin_amdgcn_readlane(__float_as_int(v), lane));
}

// One wave (64 lanes) per batch element. Lane j<50 owns hidden unit j and its
// four gate rows of W_hh, kept in VGPRs (4*50 = 200 floats). The recurrence is
// pure register/VALU: h_k is broadcast via v_readlane (SGPR operand to the
// FMAs) -- no LDS, no barriers, no lgkmcnt stall in the T-loop.
__global__ __launch_bounds__(256, 2)
void lstm_fused(const float* __restrict__ x,
                const float* __restrict__ W_ih,
                const float* __restrict__ W_hh,
                const float* __restrict__ b_ih,
                const float* __restrict__ b_hh,
                const float* __restrict__ W_lin,
                const float* __restrict__ b_lin,
                float* __restrict__ out)
{
    __shared__ float xs[4 * TSZ];     // staged x for this block's 4 batches

    const int tid = threadIdx.x;
    const int w   = tid >> 6;         // wave id within block (0..3)
    const int j   = tid & 63;         // lane id
    const int b   = blockIdx.x * 4 + w;

    // Coalesced stage of x[b0..b0+3][0..T): block-flat layout matches global.
    const float* xg = x + (size_t)blockIdx.x * 4 * TSZ;
    for (int idx = tid; idx < 4 * TSZ; idx += 256)
        xs[idx] = xg[idx];

    const bool active = (j < HSZ);
    const int  jj     = active ? j : 0;

    // Per-lane weights in registers. Inactive lanes get zeros -> their h stays
    // finite (0) and is never read (readlane only touches lanes 0..49).
    float wreg[4][HSZ];
    float wih[4], bias[4];
#pragma unroll
    for (int g = 0; g < 4; ++g) {
        const int row = g * HSZ + jj;             // PyTorch gate order i,f,g,o
        const float2* rp = (const float2*)(W_hh + row * HSZ);  // 8B-aligned rows
#pragma unroll
        for (int p = 0; p < 25; ++p) {
            float2 v = rp[p];
            wreg[g][2*p]   = active ? v.x : 0.0f;
            wreg[g][2*p+1] = active ? v.y : 0.0f;
        }
        wih[g]  = active ? W_ih[row] : 0.0f;
        bias[g] = active ? (b_ih[row] + b_hh[row]) : 0.0f;
    }

    float h = 0.0f, c = 0.0f;
    __syncthreads();                  // xs ready
    const float* xw = &xs[w * TSZ];

#pragma unroll 1
    for (int t = 0; t < TSZ; ++t) {
        const float xv = xw[t];       // issued now, consumed after the k-loop

        // Two accumulator chains per gate (8 independent FMA chains).
        float a0[4], a1[4];
#pragma unroll
        for (int g = 0; g < 4; ++g) { a0[g] = bias[g]; a1[g] = 0.0f; }

        // gates[g] += sum_k h_k * W_hh[g*50+j][k]; h_k broadcast via readlane.
#pragma unroll
        for (int k = 0; k < HSZ; k += 2) {
            const float hk0 = rl(h, k);
            const float hk1 = rl(h, k + 1);
#pragma unroll
            for (int g = 0; g < 4; ++g) {
                a0[g] = fmaf(hk0, wreg[g][k],     a0[g]);
                a1[g] = fmaf(hk1, wreg[g][k + 1], a1[g]);
            }
        }

        float gate[4];
#pragma unroll
        for (int g = 0; g < 4; ++g)
            gate[g] = fmaf(xv, wih[g], a0[g] + a1[g]);

        const float gi = fast_sig (gate[0]);
        const float gf = fast_sig (gate[1]);
        const float gg = fast_tanh(gate[2]);
        const float go = fast_sig (gate[3]);
        c = fmaf(gf, c, gi * gg);
        h = go * fast_tanh(c);
    }

    // out[b] = dot(h_T, W_lin) + b_lin  (inactive lanes hold wl==0)
    const float wl = active ? W_lin[j] : 0.0f;
    float p = h * wl;
#pragma unroll
    for (int off = 32; off > 0; off >>= 1)
        p += __shfl_down(p, off, 64);
    if (j == 0) out[b] = p + b_lin[0];
}

extern "C" void kernel_launch(void* const* d_in, const int* in_sizes, int n_in,
                              void* d_out, int out_size, void* d_ws, size_t ws_size,
                              hipStream_t stream) {
    const float* x     = (const float*)d_in[0];
    const float* W_ih  = (const float*)d_in[1];
    const float* W_hh  = (const float*)d_in[2];
    const float* b_ih  = (const float*)d_in[3];
    const float* b_hh  = (const float*)d_in[4];
    const float* W_lin = (const float*)d_in[5];
    const float* b_lin = (const float*)d_in[6];
    float* outp = (float*)d_out;

    const int B = in_sizes[0] / TSZ;   // 2048 for this problem (divisible by 4)
    hipLaunchKernelGGL(lstm_fused, dim3(B / 4), dim3(256), 0, stream,
                       x, W_ih, W_hh, b_ih, b_hh, W_lin, b_lin, outp);
}

// Round 4
// 390.949 us; speedup vs baseline: 1.1199x; 1.1199x over previous
//
#include <hip/hip_runtime.h>

#define HSZ 50
#define TSZ 512

typedef _Float16 half2_t __attribute__((ext_vector_type(2)));

// sigmoid(x) = 1/(1+exp(-x)); robust at extremes (exp->inf => 0, exp->0 => 1)
__device__ __forceinline__ float fast_sig(float x) {
    return __builtin_amdgcn_rcpf(1.0f + __expf(-x));
}
// tanh(x) = 1 - 2/(exp(2x)+1); robust at extremes (exp->inf => 1, exp->0 => -1)
__device__ __forceinline__ float fast_tanh(float x) {
    return fmaf(-2.0f, __builtin_amdgcn_rcpf(1.0f + __expf(2.0f * x)), 1.0f);
}

// Neighbor value across lane^1 via DPP quad_perm [1,0,3,2] (pure VALU, 1 instr,
// no LDS pipe). All lanes are active in the T-loop, so bound_ctrl is moot.
__device__ __forceinline__ float nbr_xor1(float v) {
    return __int_as_float(__builtin_amdgcn_update_dpp(
        0, __float_as_int(v), 0xB1, 0xF, 0xF, true));
}

__device__ __forceinline__ half2_t u_as_h2(unsigned u) {
    union { unsigned u; half2_t h; } c; c.u = u; return c.h;
}
__device__ __forceinline__ unsigned h2_as_u(half2_t h) {
    union { half2_t h; unsigned u; } c; c.h = h; return c.u;
}

// One wave per batch element; lane j<50 owns hidden unit j and its 4 gate rows
// of W_hh as packed half2 (4*25 = 100 VGPRs -- small enough that nothing falls
// into AGPRs, which was the R1/R2 tax). Matvec = v_dot2_f32_f16 (2 MACs/instr,
// fp32 accumulate). The recurrence is register-only: each lane packs
// {h_j, h_{j^1}} (DPP + RNE cvt + pack), and 25 v_readlane broadcasts of the
// packed dword feed the dot2s as wave-uniform SGPR operands. No LDS, no
// barriers, no aliasing. State h,c and everything else stays fp32.
__global__ __launch_bounds__(256, 2)
void lstm_fused(const float* __restrict__ x,
                const float* __restrict__ W_ih,
                const float* __restrict__ W_hh,
                const float* __restrict__ b_ih,
                const float* __restrict__ b_hh,
                const float* __restrict__ W_lin,
                const float* __restrict__ b_lin,
                float* __restrict__ out)
{
    __shared__ float xs[4 * TSZ];     // staged x for this block's 4 batches

    const int tid = threadIdx.x;
    const int w   = tid >> 6;         // wave id within block (0..3)
    const int j   = tid & 63;         // lane id
    const int b   = blockIdx.x * 4 + w;

    // Coalesced stage of x[b0..b0+3][0..T): block-flat layout matches global.
    const float* xg = x + (size_t)blockIdx.x * 4 * TSZ;
    for (int idx = tid; idx < 4 * TSZ; idx += 256)
        xs[idx] = xg[idx];

    const bool active = (j < HSZ);
    const int  jj     = active ? j : 0;   // clamp: inactive lanes run unit 0's
                                          // bounded dynamics; never read back.

    // Weights as packed half2 (RNE device converts). 100 VGPRs total.
    half2_t w2[4][25];
    float   wih[4], bias[4];
#pragma unroll
    for (int g = 0; g < 4; ++g) {
        const int row = g * HSZ + jj;                  // PyTorch order i,f,g,o
        const float2* rp = (const float2*)(W_hh + row * HSZ);   // 8B-aligned
#pragma unroll
        for (int p = 0; p < 25; ++p) {
            float2 v = rp[p];
            w2[g][p] = half2_t{(_Float16)v.x, (_Float16)v.y};
        }
        wih[g]  = W_ih[row];
        bias[g] = b_ih[row] + b_hh[row];
    }

    float h = 0.0f, c = 0.0f;
    __syncthreads();                  // xs ready
    const float* xw = &xs[w * TSZ];

#pragma unroll 1
    for (int t = 0; t < TSZ; ++t) {
        const float xv = xw[t];       // issued early, consumed after the dots

        // Pack {h_j, h_{j^1}} -> even lane 2m holds {h_2m, h_2m+1}.
        const float hn = nbr_xor1(h);
        const unsigned hpk = h2_as_u(half2_t{(_Float16)h, (_Float16)hn});

        // Two fp32 dot2 chains per gate (8 independent chains).
        float a0[4], a1[4];
#pragma unroll
        for (int g = 0; g < 4; ++g) { a0[g] = fmaf(xv, wih[g], bias[g]); a1[g] = 0.0f; }

#pragma unroll
        for (int p = 0; p < 25; ++p) {
            const half2_t hb = u_as_h2(
                (unsigned)__builtin_amdgcn_readlane((int)hpk, 2 * p));
            if (p & 1) {
#pragma unroll
                for (int g = 0; g < 4; ++g)
                    a1[g] = __builtin_amdgcn_fdot2(w2[g][p], hb, a1[g], false);
            } else {
#pragma unroll
                for (int g = 0; g < 4; ++g)
                    a0[g] = __builtin_amdgcn_fdot2(w2[g][p], hb, a0[g], false);
            }
        }

        const float gi = fast_sig (a0[0] + a1[0]);
        const float gf = fast_sig (a0[1] + a1[1]);
        const float gg = fast_tanh(a0[2] + a1[2]);
        const float go = fast_sig (a0[3] + a1[3]);
        c = fmaf(gf, c, gi * gg);
        h = go * fast_tanh(c);
    }

    // out[b] = dot(h_T, W_lin) + b_lin  (inactive lanes masked via wl = 0;
    // their h is bounded -- clamped-row dynamics -- so no NaN risk)
    const float wl = active ? W_lin[j] : 0.0f;
    float p = h * wl;
#pragma unroll
    for (int off = 32; off > 0; off >>= 1)
        p += __shfl_down(p, off, 64);
    if (j == 0) out[b] = p + b_lin[0];
}

extern "C" void kernel_launch(void* const* d_in, const int* in_sizes, int n_in,
                              void* d_out, int out_size, void* d_ws, size_t ws_size,
                              hipStream_t stream) {
    const float* x     = (const float*)d_in[0];
    const float* W_ih  = (const float*)d_in[1];
    const float* W_hh  = (const float*)d_in[2];
    const float* b_ih  = (const float*)d_in[3];
    const float* b_hh  = (const float*)d_in[4];
    const float* W_lin = (const float*)d_in[5];
    const float* b_lin = (const float*)d_in[6];
    float* outp = (float*)d_out;

    const int B = in_sizes[0] / TSZ;   // 2048 for this problem (divisible by 4)
    hipLaunchKernelGGL(lstm_fused, dim3(B / 4), dim3(256), 0, stream,
                       x, W_ih, W_hh, b_ih, b_hh, W_lin, b_lin, outp);
}